// Round 8
// baseline (142.839 us; speedup 1.0000x reference)
//
#include <hip/hip_runtime.h>
#include <hip/hip_bf16.h>
#include <math.h>

#define D    64
#define F3   192
#define FS   128          // stored feats channels: [sum(64) | max(64)]
#define NPB  256          // nodes per bucket (local dst = 8 bits)
#define LBITS 8
#define SBITS 17          // src id fits in 17 bits (N=100000 < 131072)
#define NBLK 256          // edge blocks for binning passes
#define SCAN_CHUNK 2048   // 256 threads * 8 elements (== 1<<11)

using bf16x8 = __attribute__((ext_vector_type(8))) short;
using u16x8  = __attribute__((ext_vector_type(8))) unsigned short;
using f32x4  = __attribute__((ext_vector_type(4))) float;

__device__ __forceinline__ ushort f2bf(float f) {
    __hip_bfloat16 h = __float2bfloat16(f);
    return *reinterpret_cast<ushort*>(&h);
}
__device__ __forceinline__ float bf2f(ushort u) {
    unsigned v = ((unsigned)u) << 16;
    return __uint_as_float(v);
}

// ---------------- Pre-cast: x and W to bf16 (one kernel) ----------------
__global__ __launch_bounds__(256) void k_cast(
    const float* __restrict__ x, ushort* __restrict__ xb, int n4,
    const float* __restrict__ W, ushort* __restrict__ Wb, int nW)
{
    if ((int)blockIdx.x < (n4 + 255) / 256) {
        int i = blockIdx.x * 256 + threadIdx.x;
        if (i < n4) {
            float4 v = *reinterpret_cast<const float4*>(x + (size_t)i * 4);
            ushort4 u = { f2bf(v.x), f2bf(v.y), f2bf(v.z), f2bf(v.w) };
            *reinterpret_cast<ushort4*>(xb + (size_t)i * 4) = u;
        }
    } else {
        for (int i = threadIdx.x; i < nW; i += 256) Wb[i] = f2bf(W[i]);
    }
}

// ---------------- Phase A: bucketed CSR construction ----------------

__global__ __launch_bounds__(256) void k_bin_hist(
    const int* __restrict__ dstv, unsigned* __restrict__ bcntT,
    int E, int EPB, int NB)
{
    __shared__ unsigned h[512];
    for (int i = threadIdx.x; i < NB; i += 256) h[i] = 0;
    __syncthreads();
    int lo = blockIdx.x * EPB, hi = min(E, lo + EPB);
    for (int e = lo + threadIdx.x; e < hi; e += 256)
        atomicAdd(&h[((unsigned)dstv[e]) >> LBITS], 1u);
    __syncthreads();
    for (int i = threadIdx.x; i < NB; i += 256)
        bcntT[(size_t)i * NBLK + blockIdx.x] = h[i];
}

__global__ __launch_bounds__(256) void k_chunk_scan(
    const unsigned* __restrict__ cnt, unsigned* __restrict__ offs,
    unsigned* __restrict__ partials, int N)
{
    __shared__ unsigned ts[256];
    int t = threadIdx.x;
    int ebase = blockIdx.x * SCAN_CHUNK + t * 8;
    unsigned v[8];
    unsigned s = 0;
    #pragma unroll
    for (int j = 0; j < 8; ++j) {
        unsigned c = (ebase + j < N) ? cnt[ebase + j] : 0u;
        v[j] = s; s += c;
    }
    ts[t] = s;
    __syncthreads();
    #pragma unroll
    for (int off = 1; off < 256; off <<= 1) {
        unsigned add = (t >= off) ? ts[t - off] : 0u;
        __syncthreads();
        ts[t] += add;
        __syncthreads();
    }
    unsigned tb = (t > 0) ? ts[t - 1] : 0u;
    #pragma unroll
    for (int j = 0; j < 8; ++j)
        if (ebase + j < N) offs[ebase + j] = tb + v[j];
    if (t == 255) partials[blockIdx.x] = ts[255];
}

__global__ void k_scan_partials(unsigned* partials, int n)
{
    if (blockIdx.x == 0 && threadIdx.x == 0) {
        unsigned s = 0;
        for (int i = 0; i < n; ++i) { unsigned c = partials[i]; partials[i] = s; s += c; }
    }
}

// cursor init folds in the chunk-partial add (no k_add_base pass).
__global__ __launch_bounds__(256) void k_bin_scatter(
    const int* __restrict__ srcv, const int* __restrict__ dstv,
    const unsigned* __restrict__ bbaseT, const unsigned* __restrict__ partials,
    unsigned* __restrict__ binned, int E, int EPB, int NB)
{
    __shared__ unsigned cur[512];
    for (int i = threadIdx.x; i < NB; i += 256) {
        unsigned idx = (unsigned)i * NBLK + blockIdx.x;
        cur[i] = bbaseT[idx] + partials[idx >> 11];
    }
    __syncthreads();
    int lo = blockIdx.x * EPB, hi = min(E, lo + EPB);
    for (int e = lo + threadIdx.x; e < hi; e += 256) {
        unsigned d = (unsigned)dstv[e];
        unsigned s = (unsigned)srcv[e];
        unsigned p = atomicAdd(&cur[d >> LBITS], 1u);
        binned[p] = ((d & (NPB - 1u)) << SBITS) | s;
    }
}

__global__ __launch_bounds__(256) void k_bucket_csr(
    const unsigned* __restrict__ binned, const unsigned* __restrict__ bbaseT,
    const unsigned* __restrict__ partials,
    unsigned* __restrict__ offs, unsigned* __restrict__ cnt,
    unsigned* __restrict__ ssrc, int E, int NB, int N)
{
    __shared__ unsigned c[256];
    __shared__ unsigned ts[256];
    int k = blockIdx.x;
    int t = threadIdx.x;
    unsigned i0 = (unsigned)k * NBLK;
    unsigned bstart = bbaseT[i0] + partials[i0 >> 11];
    unsigned bend;
    if (k + 1 < NB) {
        unsigned i1 = (unsigned)(k + 1) * NBLK;
        bend = bbaseT[i1] + partials[i1 >> 11];
    } else bend = (unsigned)E;

    c[t] = 0;
    __syncthreads();
    for (unsigned e = bstart + t; e < bend; e += 256)
        atomicAdd(&c[binned[e] >> SBITS], 1u);
    __syncthreads();

    unsigned myc = c[t];
    ts[t] = myc;
    __syncthreads();
    #pragma unroll
    for (int off = 1; off < 256; off <<= 1) {
        unsigned add = (t >= off) ? ts[t - off] : 0u;
        __syncthreads();
        ts[t] += add;
        __syncthreads();
    }
    unsigned excl = t ? ts[t - 1] : 0u;

    int gn = k * NPB + t;
    if (gn < N) { offs[gn] = bstart + excl; cnt[gn] = myc; }

    c[t] = excl;
    __syncthreads();
    for (unsigned e = bstart + t; e < bend; e += 256) {
        unsigned u  = binned[e];
        unsigned ld = u >> SBITS;
        unsigned r  = atomicAdd(&c[ld], 1u);
        ssrc[bstart + r] = u & ((1u << SBITS) - 1u);
    }
}

// ---------------- Phase B: gather (wave = node, 16 rows in flight) --------
// 8 lane-groups x 8 lanes; group g handles edges g, g+8, ...; each lane
// reads 16 B (8 bf16 ch) of the 128 B source row. 2-deep unroll -> 16
// outstanding row reads per wave. No LDS, no barriers, no cross-lane ops
// in the (group-divergent) loop; reduction after is wave-uniform.
// Writes [sum(64) | max(64)] bf16; mean is derived in the MLP from cnt.
__global__ __launch_bounds__(256) void k_gather2(
    const ushort*   __restrict__ xb,      // [N][64] bf16
    const unsigned* __restrict__ ssrc,
    const unsigned* __restrict__ offs,
    const unsigned* __restrict__ cnt,
    ushort*         __restrict__ feats,   // [N][128] bf16
    int N)
{
    int tid  = threadIdx.x;
    int lane = tid & 63;
    int wv   = tid >> 6;
    int grp  = lane >> 3;            // edge group 0..7
    int ch8  = (lane & 7) << 3;      // channel base 0,8,...,56

    int n = blockIdx.x * 4 + wv;
    if (n >= N) return;

    unsigned st = offs[n];
    unsigned dg = cnt[n];

    float s[8], m[8];
    #pragma unroll
    for (int j = 0; j < 8; ++j) { s[j] = 0.0f; m[j] = -INFINITY; }

    unsigned i = (unsigned)grp;
    for (; i + 8 < dg; i += 16) {
        unsigned s0 = ssrc[st + i];
        unsigned s1 = ssrc[st + i + 8];
        u16x8 a = *reinterpret_cast<const u16x8*>(xb + (size_t)s0 * D + ch8);
        u16x8 b = *reinterpret_cast<const u16x8*>(xb + (size_t)s1 * D + ch8);
        #pragma unroll
        for (int j = 0; j < 8; ++j) {
            float fa = bf2f(a[j]), fb = bf2f(b[j]);
            s[j] += fa + fb;
            m[j] = fmaxf(m[j], fmaxf(fa, fb));
        }
    }
    if (i < dg) {
        unsigned s0 = ssrc[st + i];
        u16x8 a = *reinterpret_cast<const u16x8*>(xb + (size_t)s0 * D + ch8);
        #pragma unroll
        for (int j = 0; j < 8; ++j) {
            float fa = bf2f(a[j]);
            s[j] += fa;
            m[j] = fmaxf(m[j], fa);
        }
    }

    // wave-uniform cross-group reduction (8 groups -> offsets 8,16,32)
    #pragma unroll
    for (int off = 8; off <= 32; off <<= 1) {
        #pragma unroll
        for (int j = 0; j < 8; ++j) {
            s[j] += __shfl_xor(s[j], off);
            m[j] = fmaxf(m[j], __shfl_xor(m[j], off));
        }
    }

    if (grp == 0) {
        u16x8 u;
        #pragma unroll
        for (int j = 0; j < 8; ++j) u[j] = f2bf(s[j]);
        *reinterpret_cast<u16x8*>(feats + (size_t)n * FS + ch8) = u;
    } else if (grp == 1) {
        u16x8 u;
        #pragma unroll
        for (int j = 0; j < 8; ++j) u[j] = dg ? f2bf(m[j]) : (ushort)0;
        *reinterpret_cast<u16x8*>(feats + (size_t)n * FS + 64 + ch8) = u;
    }
}

// ---------------- Phase C: MFMA MLP ----------------
// out[16-tile] = [sum|mean|max] @ Wb^T + b. Block = 4 waves = 4 col-blocks;
// grid = N/16 tiles. A-row = lane&15 -> mean frag = sum frag * inv (per-lane
// scalar). 6 x mfma_f32_16x16x32_bf16.
__global__ __launch_bounds__(256) void k_mlp2(
    const ushort*   __restrict__ feats,   // [N][128] bf16
    const unsigned* __restrict__ cnt,
    const ushort*   __restrict__ Wb,      // [64][192] bf16
    const float*    __restrict__ bias,    // [64]
    float*          __restrict__ out,     // [N][64]
    int N)
{
    int tid  = threadIdx.x;
    int lane = tid & 63;
    int wv   = tid >> 6;
    int l16  = lane & 15;
    int kb   = (lane >> 4) << 3;

    int col = (wv << 4) + l16;
    const ushort* wp = Wb + (size_t)col * F3 + kb;
    bf16x8 bS0 = *reinterpret_cast<const bf16x8*>(wp);
    bf16x8 bS1 = *reinterpret_cast<const bf16x8*>(wp + 32);
    bf16x8 bM0 = *reinterpret_cast<const bf16x8*>(wp + 64);
    bf16x8 bM1 = *reinterpret_cast<const bf16x8*>(wp + 96);
    bf16x8 bX0 = *reinterpret_cast<const bf16x8*>(wp + 128);
    bf16x8 bX1 = *reinterpret_cast<const bf16x8*>(wp + 160);
    float bo = bias[col];

    int n0 = blockIdx.x << 4;            // N divisible by 16

    unsigned dgr = cnt[n0 + l16];
    float inv = dgr ? 1.0f / (float)dgr : 0.0f;

    const ushort* arow = feats + (size_t)(n0 + l16) * FS + kb;
    bf16x8 aS0 = *reinterpret_cast<const bf16x8*>(arow);
    bf16x8 aS1 = *reinterpret_cast<const bf16x8*>(arow + 32);
    bf16x8 aX0 = *reinterpret_cast<const bf16x8*>(arow + 64);
    bf16x8 aX1 = *reinterpret_cast<const bf16x8*>(arow + 96);

    bf16x8 aM0, aM1;
    #pragma unroll
    for (int j = 0; j < 8; ++j) {
        aM0[j] = (short)f2bf(bf2f((ushort)aS0[j]) * inv);
        aM1[j] = (short)f2bf(bf2f((ushort)aS1[j]) * inv);
    }

    f32x4 acc = { bo, bo, bo, bo };
    acc = __builtin_amdgcn_mfma_f32_16x16x32_bf16(aS0, bS0, acc, 0, 0, 0);
    acc = __builtin_amdgcn_mfma_f32_16x16x32_bf16(aS1, bS1, acc, 0, 0, 0);
    acc = __builtin_amdgcn_mfma_f32_16x16x32_bf16(aM0, bM0, acc, 0, 0, 0);
    acc = __builtin_amdgcn_mfma_f32_16x16x32_bf16(aM1, bM1, acc, 0, 0, 0);
    acc = __builtin_amdgcn_mfma_f32_16x16x32_bf16(aX0, bX0, acc, 0, 0, 0);
    acc = __builtin_amdgcn_mfma_f32_16x16x32_bf16(aX1, bX1, acc, 0, 0, 0);

    int rbase = n0 + ((lane >> 4) << 2);
    #pragma unroll
    for (int r = 0; r < 4; ++r)
        out[(size_t)(rbase + r) * D + col] = acc[r];
}

extern "C" void kernel_launch(void* const* d_in, const int* in_sizes, int n_in,
                              void* d_out, int out_size, void* d_ws, size_t ws_size,
                              hipStream_t stream)
{
    const float* x  = (const float*)d_in[0];
    const int*   ei = (const int*)d_in[1];
    const float* W  = (const float*)d_in[2];
    const float* b  = (const float*)d_in[3];
    float* out = (float*)d_out;

    int N = in_sizes[0] / D;
    int E = in_sizes[1] / 2;
    const int* srcv = ei;
    const int* dstv = ei + E;

    int NB  = (N + NPB - 1) / NPB;          // 391 buckets
    int EPB = (E + NBLK - 1) / NBLK;
    int M   = NB * NBLK;

    unsigned* bcntT    = (unsigned*)d_ws;          // [M]
    unsigned* bbaseT   = bcntT + M;                // [M]
    unsigned* partials = bbaseT + M;               // [64]
    unsigned* offs     = partials + 64;            // [N]
    unsigned* cnt      = offs + N;                 // [N]
    unsigned* ssrc     = cnt + N;                  // [E]
    unsigned* binned   = ssrc + E;                 // [E]
    ushort*   xb       = (ushort*)(binned + E);    // [N*64] bf16
    ushort*   Wb       = xb + (size_t)N * D;       // [64*192] bf16
    ushort*   feats    = Wb + (size_t)D * F3;      // [N*128] bf16  (~50 MB total)

    int nChunksM = (M + SCAN_CHUNK - 1) / SCAN_CHUNK;
    int n4 = N * D / 4;

    k_cast<<<(n4 + 255) / 256 + 1, 256, 0, stream>>>(x, xb, n4, W, Wb, D * F3);

    k_bin_hist<<<NBLK, 256, 0, stream>>>(dstv, bcntT, E, EPB, NB);
    k_chunk_scan<<<nChunksM, 256, 0, stream>>>(bcntT, bbaseT, partials, M);
    k_scan_partials<<<1, 64, 0, stream>>>(partials, nChunksM);
    k_bin_scatter<<<NBLK, 256, 0, stream>>>(srcv, dstv, bbaseT, partials, binned, E, EPB, NB);
    k_bucket_csr<<<NB, 256, 0, stream>>>(binned, bbaseT, partials, offs, cnt, ssrc, E, NB, N);

    k_gather2<<<(N + 3) / 4, 256, 0, stream>>>(xb, ssrc, offs, cnt, feats, N);
    k_mlp2<<<N / 16, 256, 0, stream>>>(feats, cnt, Wb, b, out, N);
}